// Round 1
// baseline (188.840 us; speedup 1.0000x reference)
//
#include <hip/hip_runtime.h>

#define KDIM 4096
#define NDIM 4096
#define BM 128
#define BN 128
#define BK 128   // bytes of K per tile (int8)

using i32x4 = __attribute__((ext_vector_type(4))) int;

__device__ __forceinline__ void g2l16(const void* g, void* l) {
  __builtin_amdgcn_global_load_lds(
      (const __attribute__((address_space(1))) void*)g,
      (__attribute__((address_space(3))) void*)l,
      16, 0, 0);
}

// ---------------- detect: is weight buffer int32-expanded (flag=1) or raw int8 (flag=0)?
__global__ void w8l_detect(const int* __restrict__ w32, int* __restrict__ flag) {
  __shared__ int s;
  const int t = threadIdx.x;
  if (t == 0) s = 1;
  __syncthreads();
  bool oob = false;
#pragma unroll
  for (int i = 0; i < 16; ++i) {
    int v = w32[t * 16 + i];
    if (v < -128 || v > 127) oob = true;
  }
  if (oob) atomicAnd(&s, 0);
  __syncthreads();
  if (t == 0) *flag = s;
}

// ---------------- pack weight to int8 in ws (16 output bytes / thread)
__global__ void w8l_pack(const void* __restrict__ wsrc, const int* __restrict__ flag,
                         signed char* __restrict__ wq) {
  const int t = blockIdx.x * blockDim.x + threadIdx.x;  // 0 .. N*K/16-1
  if (*flag) {
    const int4* s = (const int4*)wsrc;
    int4 a = s[t * 4 + 0], b = s[t * 4 + 1], c = s[t * 4 + 2], d = s[t * 4 + 3];
    int4 o;
    o.x = (a.x & 255) | ((a.y & 255) << 8) | ((a.z & 255) << 16) | ((a.w & 255) << 24);
    o.y = (b.x & 255) | ((b.y & 255) << 8) | ((b.z & 255) << 16) | ((b.w & 255) << 24);
    o.z = (c.x & 255) | ((c.y & 255) << 8) | ((c.z & 255) << 16) | ((c.w & 255) << 24);
    o.w = (d.x & 255) | ((d.y & 255) << 8) | ((d.z & 255) << 16) | ((d.w & 255) << 24);
    ((int4*)wq)[t] = o;
  } else {
    ((int4*)wq)[t] = ((const int4*)wsrc)[t];
  }
}

// ---------------- quantize activations: 16 floats / thread
__global__ void w8l_quant(const float* __restrict__ x, const float* __restrict__ xs,
                          signed char* __restrict__ xq) {
  const int t = blockIdx.x * blockDim.x + threadIdx.x;
  const float s = *xs;
  const float4* x4 = (const float4*)x;
  int4 o;
  int* op = (int*)&o;
#pragma unroll
  for (int q = 0; q < 4; ++q) {
    float4 f = x4[t * 4 + q];
    int v0 = __float2int_rn(f.x / s);
    int v1 = __float2int_rn(f.y / s);
    int v2 = __float2int_rn(f.z / s);
    int v3 = __float2int_rn(f.w / s);
    v0 = v0 < -128 ? -128 : (v0 > 127 ? 127 : v0);
    v1 = v1 < -128 ? -128 : (v1 > 127 ? 127 : v1);
    v2 = v2 < -128 ? -128 : (v2 > 127 ? 127 : v2);
    v3 = v3 < -128 ? -128 : (v3 > 127 ? 127 : v3);
    op[q] = (v0 & 255) | ((v1 & 255) << 8) | ((v2 & 255) << 16) | ((v3 & 255) << 24);
  }
  ((int4*)xq)[t] = o;
}

// ---------------- int8 MFMA GEMM: out[m][n] = (sum_k Aq[m][k]*Wq[n][k]) * cs + bias[n]
__global__ __launch_bounds__(256, 2) void w8l_gemm(
    const signed char* __restrict__ Aq, const signed char* __restrict__ Wq,
    const float* __restrict__ scale, const float* __restrict__ xscale,
    const float* __restrict__ bias, float* __restrict__ out, int nbn) {
  __shared__ signed char lds[2 * 2 * BM * BK];  // [buf][A/B][128][128] = 64 KiB

  const int tid = threadIdx.x;
  const int lane = tid & 63;
  const int wid = tid >> 6;
  const int wr = wid >> 1;   // 0..1
  const int wc = wid & 1;    // 0..1
  const int l15 = lane & 15;
  const int l4 = lane >> 4;

  const int bm = blockIdx.x / nbn;
  const int bn = blockIdx.x % nbn;
  const int m0 = bm * BM, n0 = bn * BN;

  i32x4 acc[4][4] = {};

  // staging geometry: per issue q, 256 threads move 4096 B (32 rows x 128 B).
  // lin = q*4096 + wid*1024 + lane*16 ; row r = lin>>7 ; slot c16 = (lin>>4)&7.
  // LDS dest is linear; global source column is XOR-swizzled so that
  // LDS(r, c16) holds global(r, c16 ^ (r&7)).  (rule #21: swizzle src + read, linear dest)
  const unsigned lin0 = (unsigned)(wid * 1024 + lane * 16);
  const unsigned r0 = lin0 >> 7;               // 0..31 (q adds 32 each, r&7 invariant)
  const unsigned c16 = (lin0 >> 4) & 7;
  const unsigned swcol = ((c16 ^ (r0 & 7)) << 4);
  const signed char* agbase = Aq + (size_t)(m0 + r0) * KDIM + swcol;
  const signed char* bgbase = Wq + (size_t)(n0 + r0) * KDIM + swcol;

#define STAGE(buf, kb)                                                        \
  do {                                                                        \
    const unsigned ldst = (unsigned)((buf) * 32768 + wid * 1024);             \
    _Pragma("unroll") for (int q = 0; q < 4; ++q) {                           \
      g2l16(agbase + (kb) + q * (32 * KDIM), &lds[ldst + q * 4096]);          \
      g2l16(bgbase + (kb) + q * (32 * KDIM), &lds[ldst + 16384 + q * 4096]);  \
    }                                                                         \
  } while (0)

  const int NT = KDIM / BK;  // 32
  STAGE(0, 0);

  for (int kt = 0; kt < NT; ++kt) {
    asm volatile("s_waitcnt vmcnt(0)" ::: "memory");
    __syncthreads();
    if (kt + 1 < NT) STAGE((kt + 1) & 1, (kt + 1) * BK);

    const signed char* Al = &lds[(kt & 1) * 32768];
    const signed char* Bl = Al + 16384;
#pragma unroll
    for (int s = 0; s < 2; ++s) {  // two K=64 MFMA steps per BK=128 tile
      i32x4 af[4], bf[4];
#pragma unroll
      for (int i = 0; i < 4; ++i) {
        const int r = wr * 64 + i * 16 + l15;
        const int slot = (s * 4 + l4) ^ (r & 7);
        af[i] = *(const i32x4*)(Al + r * BK + slot * 16);
      }
#pragma unroll
      for (int j = 0; j < 4; ++j) {
        const int r = wc * 64 + j * 16 + l15;
        const int slot = (s * 4 + l4) ^ (r & 7);
        bf[j] = *(const i32x4*)(Bl + r * BK + slot * 16);
      }
#pragma unroll
      for (int i = 0; i < 4; ++i)
#pragma unroll
        for (int j = 0; j < 4; ++j)
          acc[i][j] = __builtin_amdgcn_mfma_i32_16x16x64_i8(af[i], bf[j], acc[i][j], 0, 0, 0);
    }
  }

  // epilogue: C/D layout col=lane&15, row=(lane>>4)*4+reg  [m89-verified, dtype-indep]
  const float cs = scale[0] * xscale[0];
#pragma unroll
  for (int j = 0; j < 4; ++j) {
    const int n = n0 + wc * 64 + j * 16 + l15;
    const float bj = bias[n];
#pragma unroll
    for (int i = 0; i < 4; ++i) {
      const int m = m0 + wr * 64 + i * 16 + l4 * 4;
      float* o = out + (size_t)m * NDIM + n;
#pragma unroll
      for (int v = 0; v < 4; ++v)
        o[(size_t)v * NDIM] = (float)acc[i][j][v] * cs + bj;
    }
  }
#undef STAGE
}

extern "C" void kernel_launch(void* const* d_in, const int* in_sizes, int n_in,
                              void* d_out, int out_size, void* d_ws, size_t ws_size,
                              hipStream_t stream) {
  const float* x = (const float*)d_in[0];
  const void* w = d_in[1];
  const float* scale = (const float*)d_in[2];
  const float* xscale = (const float*)d_in[3];
  const float* bias = (const float*)d_in[4];
  float* out = (float*)d_out;

  const int M = in_sizes[0] / KDIM;  // 8192

  int* flag = (int*)d_ws;
  signed char* wq = (signed char*)d_ws + 256;
  signed char* aq = wq + (size_t)NDIM * KDIM;

  const size_t need = 256 + (size_t)NDIM * KDIM + (size_t)M * KDIM;
  if (ws_size < need) return;  // fails validation loudly; tells us ws is too small

  w8l_detect<<<1, 256, 0, stream>>>((const int*)w, flag);
  w8l_pack<<<(NDIM * KDIM / 16) / 256, 256, 0, stream>>>(w, flag, wq);
  w8l_quant<<<(M * KDIM / 16) / 256, 256, 0, stream>>>(x, xscale, aq);

  const int nbn = NDIM / BN;  // 32
  w8l_gemm<<<(M / BM) * nbn, 256, 0, stream>>>(aq, wq, scale, xscale, bias, out, nbn);
}

// Round 2
// 186.400 us; speedup vs baseline: 1.0131x; 1.0131x over previous
//
#include <hip/hip_runtime.h>

#define KDIM 4096
#define NDIM 4096
#define BM 256
#define BN 256
#define BK 128            // K bytes (int8) per tile
#define NTILE (KDIM / BK) // 32
#define NPAIR (NTILE * 4) // 128 staging pairs total

using i32x4 = __attribute__((ext_vector_type(4))) int;

__device__ __forceinline__ void g2l16(const void* g, void* l) {
  __builtin_amdgcn_global_load_lds(
      (const __attribute__((address_space(1))) void*)g,
      (__attribute__((address_space(3))) void*)l,
      16, 0, 0);
}

// ---------------- detect: weight buffer int32-expanded (flag=1) or raw int8 (flag=0)?
__global__ void w8l_detect(const int* __restrict__ w32, int* __restrict__ flag) {
  __shared__ int s;
  const int t = threadIdx.x;
  if (t == 0) s = 1;
  __syncthreads();
  bool oob = false;
#pragma unroll
  for (int i = 0; i < 16; ++i) {
    int v = w32[t * 16 + i];
    if (v < -128 || v > 127) oob = true;
  }
  if (oob) atomicAnd(&s, 0);
  __syncthreads();
  if (t == 0) *flag = s;
}

// ---------------- pack weight to int8 in ws (16 output bytes / thread)
__global__ void w8l_pack(const void* __restrict__ wsrc, const int* __restrict__ flag,
                         signed char* __restrict__ wq) {
  const int t = blockIdx.x * blockDim.x + threadIdx.x;
  if (*flag) {
    const int4* s = (const int4*)wsrc;
    int4 a = s[t * 4 + 0], b = s[t * 4 + 1], c = s[t * 4 + 2], d = s[t * 4 + 3];
    int4 o;
    o.x = (a.x & 255) | ((a.y & 255) << 8) | ((a.z & 255) << 16) | ((a.w & 255) << 24);
    o.y = (b.x & 255) | ((b.y & 255) << 8) | ((b.z & 255) << 16) | ((b.w & 255) << 24);
    o.z = (c.x & 255) | ((c.y & 255) << 8) | ((c.z & 255) << 16) | ((c.w & 255) << 24);
    o.w = (d.x & 255) | ((d.y & 255) << 8) | ((d.z & 255) << 16) | ((d.w & 255) << 24);
    ((int4*)wq)[t] = o;
  } else {
    ((int4*)wq)[t] = ((const int4*)wsrc)[t];
  }
}

// ---------------- quantize activations: 16 floats / thread
__global__ void w8l_quant(const float* __restrict__ x, const float* __restrict__ xs,
                          signed char* __restrict__ xq) {
  const int t = blockIdx.x * blockDim.x + threadIdx.x;
  const float s = *xs;
  const float4* x4 = (const float4*)x;
  int4 o;
  int* op = (int*)&o;
#pragma unroll
  for (int q = 0; q < 4; ++q) {
    float4 f = x4[t * 4 + q];
    int v0 = __float2int_rn(f.x / s);
    int v1 = __float2int_rn(f.y / s);
    int v2 = __float2int_rn(f.z / s);
    int v3 = __float2int_rn(f.w / s);
    v0 = v0 < -128 ? -128 : (v0 > 127 ? 127 : v0);
    v1 = v1 < -128 ? -128 : (v1 > 127 ? 127 : v1);
    v2 = v2 < -128 ? -128 : (v2 > 127 ? 127 : v2);
    v3 = v3 < -128 ? -128 : (v3 > 127 ? 127 : v3);
    op[q] = (v0 & 255) | ((v1 & 255) << 8) | ((v2 & 255) << 16) | ((v3 & 255) << 24);
  }
  ((int4*)xq)[t] = o;
}

// ---------------- 256x256 8-phase i8 GEMM (T1+T2+T3+T4+T5)
// LDS layout per buffer b (0/1): A tile at b*65536, B tile at b*65536+32768.
// Row r of a tile = 128 B = 8 slots of 16 B; slot holds global k-chunk (slot ^ (r&7))
// (inverse-swizzled global source + linear LDS dest + swizzled read; rule #21).
__global__ __launch_bounds__(512, 2) void w8l_gemm8(
    const signed char* __restrict__ Aq, const signed char* __restrict__ Wq,
    const float* __restrict__ scale, const float* __restrict__ xscale,
    const float* __restrict__ bias, float* __restrict__ out, int nbn) {
  __shared__ signed char lds[131072];

  const int tid = threadIdx.x;
  const int lane = tid & 63;
  const int wid = tid >> 6;     // 0..7
  const int wr = wid >> 2;      // 0..1  (wave tile: 128 rows)
  const int wc = wid & 3;       // 0..3  (wave tile: 64 cols)
  const int l15 = lane & 15;
  const int l4 = lane >> 4;

  // XCD-aware bijective swizzle (grid = 512, 512%8==0)
  const int nwg = gridDim.x;
  const int cpx = nwg >> 3;
  const int bid = blockIdx.x;
  const int swz = (bid & 7) * cpx + (bid >> 3);
  const int bm = swz / nbn, bn = swz % nbn;
  const int m0 = bm * BM, n0 = bn * BN;

  // staging geometry: per g2l16 issue, 512 threads move 8 KB (64 rows x 128 B).
  const unsigned lin = (unsigned)tid * 16u;
  const unsigned r_in = lin >> 7;        // 0..63
  const unsigned c16 = (lin >> 4) & 7;
  const unsigned swcol = ((c16 ^ (r_in & 7)) << 4);
  const signed char* agp = Aq + (size_t)(m0 + r_in) * KDIM + swcol;
  const signed char* wgp = Wq + (size_t)(n0 + r_in) * KDIM + swcol;
  const unsigned ldsoff_thr = r_in * 128u + c16 * 16u;

  // pair q (2 issues = 128 rows of one matrix): tile=q>>2, mat=(q>>1)&1, rowhalf=q&1
#define ISSUE_PAIR(q)                                                          \
  do {                                                                         \
    const int q_ = (q);                                                        \
    if (q_ < NPAIR) {                                                          \
      const int tile_ = q_ >> 2;                                               \
      const int mat_ = (q_ >> 1) & 1;                                          \
      const int rb_ = (q_ & 1) * 128;                                          \
      const signed char* gp_ = (mat_ ? wgp : agp) + ((size_t)rb_ << 12) + tile_ * 128; \
      signed char* lp_ = lds + (unsigned)(tile_ & 1) * 65536u +                \
                         (unsigned)mat_ * 32768u + (unsigned)rb_ * 128u + ldsoff_thr; \
      g2l16(gp_, lp_);                                                         \
      g2l16(gp_ + ((size_t)64 << 12), lp_ + 8192);                             \
    }                                                                          \
  } while (0)

#define LDFRAG(base, row, s) \
  (*(const i32x4*)((base) + (row) * 128 + ((((s)*4 + l4) ^ ((row) & 7)) * 16)))

  i32x4 acc[8][4] = {};

  // prologue: tile0 all 4 pairs + tile1 pair#0
  ISSUE_PAIR(0); ISSUE_PAIR(1); ISSUE_PAIR(2); ISSUE_PAIR(3); ISSUE_PAIR(4);
  asm volatile("s_waitcnt vmcnt(2)" ::: "memory");
  __builtin_amdgcn_s_barrier();

#pragma unroll 1
  for (int kt = 0; kt < NTILE; ++kt) {
    const signed char* Ab = &lds[(kt & 1) * 65536];
    const signed char* Bb = Ab + 32768;
    i32x4 a0[4][2], a1[4][2], b01[2][2], b23[2][2];

    // ---- P1: read af[0..3], bf[0,1]; MFMA Q(0,0)
#pragma unroll
    for (int i = 0; i < 4; ++i)
#pragma unroll
      for (int s = 0; s < 2; ++s) a0[i][s] = LDFRAG(Ab, wr * 128 + i * 16 + l15, s);
#pragma unroll
    for (int j = 0; j < 2; ++j)
#pragma unroll
      for (int s = 0; s < 2; ++s) b01[j][s] = LDFRAG(Bb, wc * 64 + j * 16 + l15, s);
    ISSUE_PAIR(4 * kt + 5);
    __builtin_amdgcn_s_barrier();
    asm volatile("s_waitcnt lgkmcnt(0)" ::: "memory");
    __builtin_amdgcn_sched_barrier(0);
    __builtin_amdgcn_s_setprio(1);
#pragma unroll
    for (int i = 0; i < 4; ++i)
#pragma unroll
      for (int j = 0; j < 2; ++j)
#pragma unroll
        for (int s = 0; s < 2; ++s)
          acc[i][j] = __builtin_amdgcn_mfma_i32_16x16x64_i8(a0[i][s], b01[j][s], acc[i][j], 0, 0, 0);
    __builtin_amdgcn_s_setprio(0);
    __builtin_amdgcn_s_barrier();

    // ---- P2: read bf[2,3]; MFMA Q(0,1)
#pragma unroll
    for (int j = 0; j < 2; ++j)
#pragma unroll
      for (int s = 0; s < 2; ++s) b23[j][s] = LDFRAG(Bb, wc * 64 + (j + 2) * 16 + l15, s);
    ISSUE_PAIR(4 * kt + 6);
    __builtin_amdgcn_s_barrier();
    asm volatile("s_waitcnt lgkmcnt(0)" ::: "memory");
    __builtin_amdgcn_sched_barrier(0);
    __builtin_amdgcn_s_setprio(1);
#pragma unroll
    for (int i = 0; i < 4; ++i)
#pragma unroll
      for (int j = 0; j < 2; ++j)
#pragma unroll
        for (int s = 0; s < 2; ++s)
          acc[i][j + 2] = __builtin_amdgcn_mfma_i32_16x16x64_i8(a0[i][s], b23[j][s], acc[i][j + 2], 0, 0, 0);
    __builtin_amdgcn_s_setprio(0);
    __builtin_amdgcn_s_barrier();

    // ---- P3: read af[4..7]; MFMA Q(1,1)
#pragma unroll
    for (int i = 0; i < 4; ++i)
#pragma unroll
      for (int s = 0; s < 2; ++s) a1[i][s] = LDFRAG(Ab, wr * 128 + (i + 4) * 16 + l15, s);
    ISSUE_PAIR(4 * kt + 7);
    __builtin_amdgcn_s_barrier();
    asm volatile("s_waitcnt lgkmcnt(0)" ::: "memory");
    __builtin_amdgcn_sched_barrier(0);
    __builtin_amdgcn_s_setprio(1);
#pragma unroll
    for (int i = 0; i < 4; ++i)
#pragma unroll
      for (int j = 0; j < 2; ++j)
#pragma unroll
        for (int s = 0; s < 2; ++s)
          acc[i + 4][j + 2] = __builtin_amdgcn_mfma_i32_16x16x64_i8(a1[i][s], b23[j][s], acc[i + 4][j + 2], 0, 0, 0);
    __builtin_amdgcn_s_setprio(0);
    __builtin_amdgcn_s_barrier();

    // ---- P4: no ds_read; issue tile t+2 pair#0 (safe: all tile-t reads done at P3 barrier);
    //          counted vmcnt — tile t+1 fully landed, 1 pair stays in flight. MFMA Q(1,0)
    ISSUE_PAIR(4 * kt + 8);
    if (kt < NTILE - 2) {
      asm volatile("s_waitcnt vmcnt(2)" ::: "memory");
    } else {
      asm volatile("s_waitcnt vmcnt(0)" ::: "memory");
    }
    __builtin_amdgcn_s_barrier();
    __builtin_amdgcn_sched_barrier(0);
    __builtin_amdgcn_s_setprio(1);
#pragma unroll
    for (int i = 0; i < 4; ++i)
#pragma unroll
      for (int j = 0; j < 2; ++j)
#pragma unroll
        for (int s = 0; s < 2; ++s)
          acc[i + 4][j] = __builtin_amdgcn_mfma_i32_16x16x64_i8(a1[i][s], b01[j][s], acc[i + 4][j], 0, 0, 0);
    __builtin_amdgcn_s_setprio(0);
    __builtin_amdgcn_s_barrier();
  }

  // epilogue: C/D layout col=lane&15, row=(lane>>4)*4+reg  [m89-verified, dtype-indep]
  const float cs = scale[0] * xscale[0];
#pragma unroll
  for (int j = 0; j < 4; ++j) {
    const int n = n0 + wc * 64 + j * 16 + l15;
    const float bj = bias[n];
#pragma unroll
    for (int i = 0; i < 8; ++i) {
      const int m = m0 + wr * 128 + i * 16 + l4 * 4;
      float* o = out + (size_t)m * NDIM + n;
#pragma unroll
      for (int v = 0; v < 4; ++v)
        o[(size_t)v * NDIM] = (float)acc[i][j][v] * cs + bj;
    }
  }
#undef ISSUE_PAIR
#undef LDFRAG
}

extern "C" void kernel_launch(void* const* d_in, const int* in_sizes, int n_in,
                              void* d_out, int out_size, void* d_ws, size_t ws_size,
                              hipStream_t stream) {
  const float* x = (const float*)d_in[0];
  const void* w = d_in[1];
  const float* scale = (const float*)d_in[2];
  const float* xscale = (const float*)d_in[3];
  const float* bias = (const float*)d_in[4];
  float* out = (float*)d_out;

  const int M = in_sizes[0] / KDIM;  // 8192

  int* flag = (int*)d_ws;
  signed char* wq = (signed char*)d_ws + 256;
  signed char* aq = wq + (size_t)NDIM * KDIM;

  const size_t need = 256 + (size_t)NDIM * KDIM + (size_t)M * KDIM;
  if (ws_size < need) return;

  w8l_detect<<<1, 256, 0, stream>>>((const int*)w, flag);
  w8l_pack<<<(NDIM * KDIM / 16) / 256, 256, 0, stream>>>(w, flag, wq);
  w8l_quant<<<(M * KDIM / 16) / 256, 256, 0, stream>>>(x, xscale, aq);

  const int nbn = NDIM / BN;  // 16
  w8l_gemm8<<<(M / BM) * nbn, 512, 0, stream>>>(aq, wq, scale, xscale, bias, out, nbn);
}